// Round 10
// baseline (199.509 us; speedup 1.0000x reference)
//
#include <hip/hip_runtime.h>
#include <math.h>

#define BB 32
#define KK 64
#define HH 96
#define WW 128
#define HW (HH*WW)             // 12288
#define MAP_SIZE (BB*KK*HW)    // 25165824
#define NBK (BB*KK)            // 2048
#define NT  (HW/256)           // 48 pixel-tiles per image
#define NPX (BB*HW)            // 393216 pixels total
#define SST 259                // LDS row stride (floats): <=3-way banks everywhere

// ---------------- Kernel 1: pure READ — per-pixel softmax denominator -------------
// Diagnostic + optimization: isolate the 100-MB strided read stream so DRAM serves
// only one direction. Thread-per-pixel, 4 batches of 16 independent loads (deep MLP,
// ~40 VGPR -> high occupancy). den in the same serial k-order as every passing
// round -> inv bit-identical -> map bits unchanged. Side effect: x is now resident
// in the 256-MB LLC for map_k.
__global__ __launch_bounds__(256) void den_k(const float* __restrict__ x,
                                             float* __restrict__ invd) {
    int blk  = blockIdx.x;
    int b    = blk / NT;
    int tile = blk - b * NT;
    int t    = threadIdx.x;
    size_t base = (size_t)b * (KK * HW) + (size_t)tile * 256 + t;

    float den = 0.f;
    #pragma unroll
    for (int c = 0; c < 4; ++c) {
        float v[16];
        #pragma unroll
        for (int j = 0; j < 16; ++j)               // 16 loads in flight, no deps
            v[j] = x[base + (size_t)(c * 16 + j) * HW];
        #pragma unroll
        for (int j = 0; j < 16; ++j)               // serial k-order: 0..63 overall
            den += __expf(v[j]);
    }
    invd[(size_t)blk * 256 + t] = 1.f / den;       // coalesced 1.6 MB write
}

// ---------------- Kernel 2: WRITE-dominated — map + per-(b,k) reductions ----------
// x re-read hits LLC (just streamed by den_k; NT map stores bypass LLC so x stays
// resident). m = __expf(x)*inv — bit-identical to round-7's passing kernel. Then
// r7's verified LDS-staged fp32 transposed reduce + fp64 atomics.
__global__ __launch_bounds__(256, 2) void map_k(const float* __restrict__ x,
                                                const float* __restrict__ invd,
                                                float* __restrict__ out,
                                                double* __restrict__ sxyz) {
    __shared__ float sm[KK][SST];

    int blk  = blockIdx.x;
    int b    = blk / NT;
    int tile = blk - b * NT;
    int t    = threadIdx.x;
    size_t base = (size_t)b * (KK * HW) + (size_t)tile * 256 + t;

    float inv = invd[(size_t)blk * 256 + t];

    // Normalize + NT-store (streaming writes; nothing re-reads the map) and stage
    // m in LDS for the transpose. LDS write bank = (3k+t)&31 -> 2-way, free.
    #pragma unroll
    for (int k = 0; k < KK; ++k) {
        float m = __expf(x[base + (size_t)k * HW]) * inv;
        __builtin_nontemporal_store(m, &out[base + (size_t)k * HW]);
        sm[k][t] = m;
    }
    __syncthreads();

    // Transposed reduction from LDS, fp32 (r6/r7-verified math, identical order).
    // Thread (k = t>>2, q = t&3) reduces 64 px of channel k.
    int k = t >> 2;
    int q = t & 3;
    const float gy_base = (float)(tile * 2);
    float z = 0.f, sx = 0.f, sy = 0.f;
    #pragma unroll
    for (int j = 0; j < 16; ++j) {
        int p0 = q * 4 + j * 16;                // p0..p0+3 share a row (no wrap)
        float m0 = sm[k][p0 + 0];
        float m1 = sm[k][p0 + 1];
        float m2 = sm[k][p0 + 2];
        float m3 = sm[k][p0 + 3];
        float s = (m0 + m1) + (m2 + m3);
        z  += s;
        sx += fmaf(s, (float)(p0 & (WW - 1)), fmaf(3.f, m3, fmaf(2.f, m2, m1)));
        sy += s * (gy_base + (float)(p0 >> 7));
    }

    z  += __shfl_xor(z,  1, 64);  z  += __shfl_xor(z,  2, 64);
    sx += __shfl_xor(sx, 1, 64);  sx += __shfl_xor(sx, 2, 64);
    sy += __shfl_xor(sy, 1, 64);  sy += __shfl_xor(sy, 2, 64);
    if (q == 0) {
        int bk = b * KK + k;
        atomicAdd(&sxyz[bk * 3 + 0], (double)sx);
        atomicAdd(&sxyz[bk * 3 + 1], (double)sy);
        atomicAdd(&sxyz[bk * 3 + 2], (double)z);
    }
}

// ---------------- Keypoints: inclusive fp64 scan over flattened (b,k) ----------------
__global__ __launch_bounds__(256) void keypoint_k(const double* __restrict__ sxyz,
                                                  float* __restrict__ kp,
                                                  float* __restrict__ zeta) {
    const int PT = NBK / 256;   // 8
    int t = threadIdx.x;
    int lane = t & 63, wid = t >> 6;

    double vx[PT], vy[PT], vz[PT];
    double cx = 0.0, cy = 0.0;
    #pragma unroll
    for (int e = 0; e < PT; ++e) {
        int idx = t * PT + e;
        cx += sxyz[idx * 3 + 0]; vx[e] = cx;
        cy += sxyz[idx * 3 + 1]; vy[e] = cy;
        vz[e] = sxyz[idx * 3 + 2];
    }
    double tx = cx, ty = cy;
    for (int off = 1; off < 64; off <<= 1) {
        double ax = __shfl_up(tx, off, 64);
        double ay = __shfl_up(ty, off, 64);
        if (lane >= off) { tx += ax; ty += ay; }
    }
    __shared__ double wxs[4], wys[4];
    if (lane == 63) { wxs[wid] = tx; wys[wid] = ty; }
    __syncthreads();
    double offx = tx - cx, offy = ty - cy;
    for (int w2 = 0; w2 < wid; ++w2) { offx += wxs[w2]; offy += wys[w2]; }

    #pragma unroll
    for (int e = 0; e < PT; ++e) {
        int idx = t * PT + e;
        double zz = vz[e];
        double kx = rint((vx[e] + offx) / zz);
        double ky = rint((vy[e] + offy) / zz);
        float fkx = (float)kx, fky = (float)ky;
        if (fkx > 128.0f || fkx < 0.0f) fkx = 64.0f;   // PRE_WIDTH clamp -> center
        if (fky > 96.0f  || fky < 0.0f) fky = 48.0f;   // PRE_HEIGHT clamp -> center
        kp[idx * 2 + 0] = fkx;
        kp[idx * 2 + 1] = fky;
        zeta[idx] = (float)zz;
    }
}

extern "C" void kernel_launch(void* const* d_in, const int* in_sizes, int n_in,
                              void* d_out, int out_size, void* d_ws, size_t ws_size,
                              hipStream_t stream) {
    const float* x = (const float*)d_in[0];
    float* out  = (float*)d_out;
    float* map  = out;                         // [B,K,H,W]
    float* kp   = out + MAP_SIZE;              // [B,K,2]
    float* zeta = out + MAP_SIZE + NBK * 2;    // [B,K]
    double* sxyz = (double*)d_ws;              // [NBK][3] fp64 accumulators
    float*  invd = (float*)((char*)d_ws + 65536);   // [NPX] 1/den, 1.57 MB

    hipMemsetAsync(d_ws, 0, (size_t)NBK * 3 * sizeof(double), stream);
    den_k     <<< BB * NT, 256, 0, stream >>> (x, invd);
    map_k     <<< BB * NT, 256, 0, stream >>> (x, invd, map, sxyz);
    keypoint_k<<< 1,       256, 0, stream >>> (sxyz, kp, zeta);
}